// Round 2
// baseline (2104.371 us; speedup 1.0000x reference)
//
#include <hip/hip_runtime.h>

// Problem constants (CrossAttention_73856257622246)
#define NB 4      // batch
#define QC 256    // query channels
#define SD 16384  // Z*H*W spatial
#define NT 256    // tokens N
#define KVC 512   // token channels
#define TC 128    // TOKEN_CH
#define NH 4      // heads
#define DH 32     // head dim
#define TS 64     // spatial tile per block

typedef unsigned short u16;

__device__ __forceinline__ float b2f(u16 u) {
  unsigned int v = ((unsigned int)u) << 16;
  return __builtin_bit_cast(float, v);
}
__device__ __forceinline__ u16 f2b(float f) {
  unsigned int x = __builtin_bit_cast(unsigned int, f);
  unsigned int r = (x + 0x7fffu + ((x >> 16) & 1u)) >> 16;
  return (u16)r;
}

// K/V precompute: only does work when tanh(gate) != 0 (data-dependent, runs every launch)
__global__ __launch_bounds__(256) void kv_kernel(
    const float* __restrict__ tokens, const float* __restrict__ kw,
    const float* __restrict__ vw, const float* __restrict__ gate,
    float* __restrict__ ws_kv) {
  float tg = tanhf(gate[0]);
  if (tg == 0.0f) return;
  int b = blockIdx.x >> 8;
  int n = blockIdx.x & 255;
  __shared__ float tok[KVC];
  for (int c = threadIdx.x; c < KVC; c += 256)
    tok[c] = tokens[((size_t)(b * NT + n)) * KVC + c];
  __syncthreads();
  int tid = threadIdx.x;
  int t = tid & 127;
  const float* w = (tid < 128) ? kw : vw;
  const float* wr = w + (size_t)t * KVC;
  float acc = 0.f;
  for (int c = 0; c < KVC; c += 4) {
    float4 wv = *(const float4*)(wr + c);
    acc += tok[c] * wv.x + tok[c + 1] * wv.y + tok[c + 2] * wv.z + tok[c + 3] * wv.w;
  }
  int h = t >> 5, d = t & 31;
  float* dst = ws_kv + ((tid < 128) ? 0 : NB * NH * NT * DH);
  dst[(((b * NH + h) * NT) + n) * DH + d] = acc;
}

// Fused: [attention+proj+gated residual when gate!=0] + FFN + residual
__global__ __launch_bounds__(256, 3) void fused_kernel(
    const float* __restrict__ feat, const float* __restrict__ qw,
    const float* __restrict__ qb, const float* __restrict__ projw,
    const float* __restrict__ projb, const float* __restrict__ ff1w,
    const float* __restrict__ ff1b, const float* __restrict__ ff2w,
    const float* __restrict__ ff2b, const float* __restrict__ gate,
    const float* __restrict__ ws_kv, float* __restrict__ out) {
  __shared__ u16 smem[QC * TS + TC * TS];  // 48 KB: sfeat(out1) + sattn/shid (bf16)
  u16* sfeat = smem;
  u16* sattn = smem + QC * TS;

  int b = blockIdx.x >> 8;
  int s0 = (blockIdx.x & 255) * TS;
  int tid = threadIdx.x;
  int w = tid >> 6;    // wave id 0..3
  int lane = tid & 63; // spatial offset within tile

  // stage feat tile [QC][TS]: fp32 global -> bf16 LDS
  const float* fbase = feat + (((size_t)b * QC) << 14) + s0;
#pragma unroll
  for (int it = 0; it < 16; ++it) {
    int f = it * 1024 + tid * 4;
    int c = f >> 6, sl = f & 63;
    float4 v = *(const float4*)(fbase + ((size_t)c << 14) + sl);
    sfeat[f + 0] = f2b(v.x);
    sfeat[f + 1] = f2b(v.y);
    sfeat[f + 2] = f2b(v.z);
    sfeat[f + 3] = f2b(v.w);
  }
  float tg = tanhf(gate[0]);
  __syncthreads();

  if (tg != 0.0f) {
    // ---- Q for head w (wave == head), this lane's spatial position ----
    float qreg[DH];
#pragma unroll
    for (int d = 0; d < DH; d++) {
      int o = w * DH + d;
      float a = qb[o];
      const float* qr = qw + (size_t)o * QC;
      for (int c = 0; c < QC; c += 4) {
        float4 wv = *(const float4*)(qr + c);
        a += b2f(sfeat[(c + 0) * TS + lane]) * wv.x;
        a += b2f(sfeat[(c + 1) * TS + lane]) * wv.y;
        a += b2f(sfeat[(c + 2) * TS + lane]) * wv.z;
        a += b2f(sfeat[(c + 3) * TS + lane]) * wv.w;
      }
      qreg[d] = a;
    }
    // ---- online-softmax attention over NT tokens ----
    const float* Kp = ws_kv + (size_t)(b * NH + w) * NT * DH;
    const float* Vp = Kp + NB * NH * NT * DH;
    float m = -1e30f, l = 0.f;
    float oacc[DH];
#pragma unroll
    for (int d = 0; d < DH; d++) oacc[d] = 0.f;
    const float scale = 0.17677669529663687f;  // 1/sqrt(32)
    for (int n = 0; n < NT; n++) {
      const float* kr = Kp + n * DH;
      float s = 0.f;
#pragma unroll
      for (int d = 0; d < DH; d++) s += qreg[d] * kr[d];
      s *= scale;
      float nm = fmaxf(m, s);
      float p = __expf(s - nm);
      float al = __expf(m - nm);
      const float* vr = Vp + n * DH;
      l = l * al + p;
#pragma unroll
      for (int d = 0; d < DH; d++) oacc[d] = oacc[d] * al + p * vr[d];
      m = nm;
    }
    float inv = 1.0f / l;
#pragma unroll
    for (int d = 0; d < DH; d++)
      sattn[(w * DH + d) * TS + lane] = f2b(oacc[d] * inv);
    __syncthreads();  // sattn ready; all waves done reading pre-proj sfeat
    // ---- proj + gated residual, each wave overwrites its own sfeat rows ----
    for (int ci = 0; ci < 64; ci++) {
      int c = w * 64 + ci;
      float a = projb[c];
      const float* pr = projw + (size_t)c * TC;
      for (int t = 0; t < TC; t += 4) {
        float4 wv = *(const float4*)(pr + t);
        a += b2f(sattn[(t + 0) * TS + lane]) * wv.x;
        a += b2f(sattn[(t + 1) * TS + lane]) * wv.y;
        a += b2f(sattn[(t + 2) * TS + lane]) * wv.z;
        a += b2f(sattn[(t + 3) * TS + lane]) * wv.w;
      }
      float o1 = b2f(sfeat[c * TS + lane]) + tg * a;
      sfeat[c * TS + lane] = f2b(o1);
    }
    __syncthreads();  // out1 tile complete
  }

  // ---- FFN: hidden in 128-j chunks, ff2 accumulated in registers ----
  u16* shid = sattn;
  float facc[64];
#pragma unroll
  for (int ci = 0; ci < 64; ci++) facc[ci] = ff2b[w * 64 + ci];

#pragma unroll 1
  for (int chunk = 0; chunk < 4; chunk++) {
    int j0 = chunk * 128;
    // hidden rows j0 + w*32 .. +32 (8 rows/group), SiLU, -> shid (bf16)
#pragma unroll 1
    for (int jt = 0; jt < 32; jt += 8) {
      int j = j0 + w * 32 + jt;
      const float* w0 = ff1w + (size_t)j * QC;
      float a[8];
#pragma unroll
      for (int r = 0; r < 8; r++) a[r] = ff1b[j + r];
#pragma unroll 2
      for (int c = 0; c < QC; c += 4) {
        float4 wv[8];
#pragma unroll
        for (int r = 0; r < 8; r++) wv[r] = *(const float4*)(w0 + r * QC + c);
        float x0 = b2f(sfeat[(c + 0) * TS + lane]);
        float x1 = b2f(sfeat[(c + 1) * TS + lane]);
        float x2 = b2f(sfeat[(c + 2) * TS + lane]);
        float x3 = b2f(sfeat[(c + 3) * TS + lane]);
#pragma unroll
        for (int r = 0; r < 8; r++)
          a[r] += x0 * wv[r].x + x1 * wv[r].y + x2 * wv[r].z + x3 * wv[r].w;
      }
      int jl = w * 32 + jt;
#pragma unroll
      for (int r = 0; r < 8; r++) {
        float s = a[r] / (1.f + __expf(-a[r]));
        shid[(jl + r) * TS + lane] = f2b(s);
      }
    }
    __syncthreads();
    // ff2 partial: own 64 output channels (8 rows/group) x this 128-j chunk
#pragma unroll 1
    for (int ct = 0; ct < 64; ct += 8) {
      int c = w * 64 + ct;
      const float* w0 = ff2w + (size_t)c * KVC + j0;
      float a[8];
#pragma unroll
      for (int r = 0; r < 8; r++) a[r] = facc[ct + r];
#pragma unroll 2
      for (int jj = 0; jj < 128; jj += 4) {
        float4 wv[8];
#pragma unroll
        for (int r = 0; r < 8; r++) wv[r] = *(const float4*)(w0 + r * KVC + jj);
        float h0 = b2f(shid[(jj + 0) * TS + lane]);
        float h1 = b2f(shid[(jj + 1) * TS + lane]);
        float h2 = b2f(shid[(jj + 2) * TS + lane]);
        float h3 = b2f(shid[(jj + 3) * TS + lane]);
#pragma unroll
        for (int r = 0; r < 8; r++)
          a[r] += h0 * wv[r].x + h1 * wv[r].y + h2 * wv[r].z + h3 * wv[r].w;
      }
#pragma unroll
      for (int r = 0; r < 8; r++) facc[ct + r] = a[r];
    }
    __syncthreads();
  }

  // epilogue: out = out1 + ff (fp32 stores, coalesced)
#pragma unroll
  for (int ci = 0; ci < 64; ci++) {
    int c = w * 64 + ci;
    float o = b2f(sfeat[c * TS + lane]) + facc[ci];
    out[(((size_t)(b * QC + c)) << 14) + s0 + lane] = o;
  }
}

extern "C" void kernel_launch(void* const* d_in, const int* in_sizes, int n_in,
                              void* d_out, int out_size, void* d_ws, size_t ws_size,
                              hipStream_t stream) {
  const float* feat   = (const float*)d_in[0];
  const float* tokens = (const float*)d_in[1];
  const float* qw     = (const float*)d_in[2];
  const float* qb     = (const float*)d_in[3];
  const float* kw     = (const float*)d_in[4];
  const float* vw     = (const float*)d_in[5];
  const float* projw  = (const float*)d_in[6];
  const float* projb  = (const float*)d_in[7];
  const float* ff1w   = (const float*)d_in[8];
  const float* ff1b   = (const float*)d_in[9];
  const float* ff2w   = (const float*)d_in[10];
  const float* ff2b   = (const float*)d_in[11];
  const float* gate   = (const float*)d_in[12];
  float* out = (float*)d_out;
  float* ws_kv = (float*)d_ws;  // 2 * NB*NH*NT*DH floats = 1 MB (K then V)

  kv_kernel<<<dim3(NB * NT), dim3(256), 0, stream>>>(tokens, kw, vw, gate, ws_kv);
  fused_kernel<<<dim3(NB * (SD / TS)), dim3(256), 0, stream>>>(
      feat, qw, qb, projw, projb, ff1w, ff1b, ff2w, ff2b, gate, ws_kv, out);
}

// Round 3
// 204.758 us; speedup vs baseline: 10.2773x; 10.2773x over previous
//
#include <hip/hip_runtime.h>

// Problem constants (CrossAttention_73856257622246)
#define NB 4      // batch
#define QC 256    // query channels
#define SD 16384  // Z*H*W spatial per batch
#define NT 256    // tokens
#define KVC 512   // token channels
#define TC 128    // TOKEN_CH
#define NH 4      // heads
#define DH 32     // head dim
#define TSP 64    // spatial tile per block
#define XPITCH 260  // sX row pitch (256 + 4) -> bank stride 2, 8B aligned rows
#define HPITCH 132  // sH row pitch (128 + 4)

typedef unsigned short u16;
typedef __attribute__((ext_vector_type(8))) short bf16x8;  // MFMA A/B frag (4 VGPR)
typedef __attribute__((ext_vector_type(4))) short bf16x4;  // 8B half-frag
typedef __attribute__((ext_vector_type(4))) float f32x4;   // MFMA C/D frag

union ABFrag { bf16x4 h[2]; bf16x8 v; };

__device__ __forceinline__ float b2f(u16 u) {
  unsigned int v = ((unsigned int)u) << 16;
  return __builtin_bit_cast(float, v);
}
__device__ __forceinline__ u16 f2b(float f) {
  unsigned int x = __builtin_bit_cast(unsigned int, f);
  unsigned int r = (x + 0x7fffu + ((x >> 16) & 1u)) >> 16;
  return (u16)r;
}

// ---- weight pre-pack: fp32 -> bf16 in MFMA B-fragment order ----
// B-frag layout (16x16x32): lane holds B[k][n], n = lane&15, k = (lane>>4)*8 + i
// w1p slot = (jblk*8 + kblk)*64 + lane   (jblk: 32, kblk: 8)
// w2p slot = (oblk*16 + kblk)*64 + lane  (oblk: 16, kblk: 16)
__global__ __launch_bounds__(256) void pack_kernel(
    const float* __restrict__ ff1w, const float* __restrict__ ff2w,
    u16* __restrict__ w1p, u16* __restrict__ w2p) {
  int idx = blockIdx.x * 256 + threadIdx.x;  // 0..32767
  int lane = idx & 63;
  int m = lane & 15, q = lane >> 4;
  if (idx < 16384) {
    int kblk = (idx >> 6) & 7;
    int jblk = idx >> 9;
    const float* src = ff1w + (size_t)(jblk * 16 + m) * QC + kblk * 32 + q * 8;
    u16* dst = w1p + (size_t)idx * 8;
#pragma unroll
    for (int i = 0; i < 8; i++) dst[i] = f2b(src[i]);
  } else {
    int s2 = idx - 16384;
    int kblk = (s2 >> 6) & 15;
    int oblk = s2 >> 10;
    const float* src = ff2w + (size_t)(oblk * 16 + m) * KVC + kblk * 32 + q * 8;
    u16* dst = w2p + (size_t)s2 * 8;
#pragma unroll
    for (int i = 0; i < 8; i++) dst[i] = f2b(src[i]);
  }
}

// ---- K/V precompute (only does work when tanh(gate) != 0) ----
__global__ __launch_bounds__(256) void kv_kernel(
    const float* __restrict__ tokens, const float* __restrict__ kw,
    const float* __restrict__ vw, const float* __restrict__ gate,
    float* __restrict__ ws_kv) {
  float tg = tanhf(gate[0]);
  if (tg == 0.0f) return;
  int b = blockIdx.x >> 8;
  int n = blockIdx.x & 255;
  __shared__ float tok[KVC];
  for (int c = threadIdx.x; c < KVC; c += 256)
    tok[c] = tokens[((size_t)(b * NT + n)) * KVC + c];
  __syncthreads();
  int tid = threadIdx.x;
  int t = tid & 127;
  const float* w = (tid < 128) ? kw : vw;
  const float* wr = w + (size_t)t * KVC;
  float acc = 0.f;
  for (int c = 0; c < KVC; c += 4) {
    float4 wv = *(const float4*)(wr + c);
    acc += tok[c] * wv.x + tok[c + 1] * wv.y + tok[c + 2] * wv.z + tok[c + 3] * wv.w;
  }
  int h = t >> 5, d = t & 31;
  float* dst = ws_kv + ((tid < 128) ? 0 : NB * NH * NT * DH);
  dst[(((b * NH + h) * NT) + n) * DH + d] = acc;
}

// ---- fused: [attention+proj+gated residual if gate!=0] + MFMA FFN + residual ----
__global__ __launch_bounds__(256, 2) void fused_kernel(
    const float* __restrict__ feat, const float* __restrict__ qw,
    const float* __restrict__ qb, const float* __restrict__ projw,
    const float* __restrict__ projb, const float* __restrict__ ff1b,
    const float* __restrict__ ff2b, const u16* __restrict__ w1p,
    const u16* __restrict__ w2p, const float* __restrict__ gate,
    const float* __restrict__ ws_kv, float* __restrict__ out) {
  __shared__ u16 sX[TSP * XPITCH];  // feat/out1 tile, [s][c], 33280 B
  __shared__ u16 sH[TSP * HPITCH];  // hidden chunk / attn buf, [s][j], 16896 B

  int b = blockIdx.x >> 8;
  int s0 = (blockIdx.x & 255) * TSP;
  int tid = threadIdx.x;
  int w = tid >> 6;     // wave 0..3
  int lane = tid & 63;
  int lm = lane & 15, lq = lane >> 4;

  // ---- stage feat tile transposed: global [c][s] fp32 -> LDS [s][c] bf16 ----
  {
    const float* fb = feat + (((size_t)b * QC) << 14) + s0 + lane;
#pragma unroll
    for (int it = 0; it < 16; ++it) {
      int c0 = it * 16 + w * 4;
      const float* gp = fb + ((size_t)c0 << 14);
      ushort4 pk;
      pk.x = f2b(gp[0]);
      pk.y = f2b(gp[16384]);
      pk.z = f2b(gp[32768]);
      pk.w = f2b(gp[49152]);
      *(ushort4*)&sX[lane * XPITCH + c0] = pk;
    }
  }
  float tg = tanhf(gate[0]);
  __syncthreads();

  if (tg != 0.0f) {
    // ---- Q for head w, spatial position `lane` ----
    float qreg[DH];
#pragma unroll
    for (int d = 0; d < DH; d++) {
      int o = w * DH + d;
      float a = qb[o];
      const float* qr = qw + (size_t)o * QC;
      for (int c = 0; c < QC; c += 4) {
        float4 wv = *(const float4*)(qr + c);
        a += b2f(sX[lane * XPITCH + c + 0]) * wv.x;
        a += b2f(sX[lane * XPITCH + c + 1]) * wv.y;
        a += b2f(sX[lane * XPITCH + c + 2]) * wv.z;
        a += b2f(sX[lane * XPITCH + c + 3]) * wv.w;
      }
      qreg[d] = a;
    }
    // ---- online-softmax attention over NT tokens ----
    const float* Kp = ws_kv + (size_t)(b * NH + w) * NT * DH;
    const float* Vp = Kp + NB * NH * NT * DH;
    float m_ = -1e30f, l_ = 0.f;
    float oacc[DH];
#pragma unroll
    for (int d = 0; d < DH; d++) oacc[d] = 0.f;
    const float scale = 0.17677669529663687f;  // 1/sqrt(32)
    for (int n = 0; n < NT; n++) {
      const float* kr = Kp + n * DH;
      float s = 0.f;
#pragma unroll
      for (int d = 0; d < DH; d++) s += qreg[d] * kr[d];
      s *= scale;
      float nm = fmaxf(m_, s);
      float p = __expf(s - nm);
      float al = __expf(m_ - nm);
      const float* vr = Vp + n * DH;
      l_ = l_ * al + p;
#pragma unroll
      for (int d = 0; d < DH; d++) oacc[d] = oacc[d] * al + p * vr[d];
      m_ = nm;
    }
    float inv = 1.0f / l_;
#pragma unroll
    for (int d = 0; d < DH; d++)
      sH[lane * HPITCH + w * DH + d] = f2b(oacc[d] * inv);  // sattn [s][t=128]
    __syncthreads();
    // ---- proj + gated residual into sX (wave w owns channels w*64..+64) ----
    for (int ci = 0; ci < 64; ci++) {
      int c = w * 64 + ci;
      float a = projb[c];
      const float* pr = projw + (size_t)c * TC;
      for (int t = 0; t < TC; t += 4) {
        float4 wv = *(const float4*)(pr + t);
        a += b2f(sH[lane * HPITCH + t + 0]) * wv.x;
        a += b2f(sH[lane * HPITCH + t + 1]) * wv.y;
        a += b2f(sH[lane * HPITCH + t + 2]) * wv.z;
        a += b2f(sH[lane * HPITCH + t + 3]) * wv.w;
      }
      float o1 = b2f(sX[lane * XPITCH + c]) + tg * a;
      sX[lane * XPITCH + c] = f2b(o1);
    }
    __syncthreads();
  }

  // ---- MFMA FFN ----
  const f32x4 fzero = {0.f, 0.f, 0.f, 0.f};
  f32x4 acc2[4][4];  // [t = o-block][m = s-block]
#pragma unroll
  for (int t = 0; t < 4; t++)
#pragma unroll
    for (int m = 0; m < 4; m++) acc2[t][m] = fzero;

#pragma unroll 1
  for (int ch = 0; ch < 4; ++ch) {
    // GEMM1: H^T[s=64][j-chunk=128] ; wave handles j-blocks {2w, 2w+1}
    f32x4 acc1[2][4];
#pragma unroll
    for (int t = 0; t < 2; t++)
#pragma unroll
      for (int m = 0; m < 4; m++) acc1[t][m] = fzero;
#pragma unroll 2
    for (int k = 0; k < 8; ++k) {
      ABFrag a[4];
      int col = k * 32 + lq * 8;
#pragma unroll
      for (int m = 0; m < 4; m++) {
        int row = m * 16 + lm;
        a[m].h[0] = *(const bf16x4*)&sX[row * XPITCH + col];
        a[m].h[1] = *(const bf16x4*)&sX[row * XPITCH + col + 4];
      }
#pragma unroll
      for (int t = 0; t < 2; t++) {
        int jblk = ch * 8 + w * 2 + t;
        bf16x8 bf = *(const bf16x8*)(w1p + (((size_t)jblk * 8 + k) * 64 + lane) * 8);
#pragma unroll
        for (int m = 0; m < 4; m++)
          acc1[t][m] = __builtin_amdgcn_mfma_f32_16x16x32_bf16(a[m].v, bf, acc1[t][m], 0, 0, 0);
      }
    }
    __syncthreads();  // previous chunk's GEMM2 reads of sH complete
    // bias + SiLU -> sH[s][j_local]
#pragma unroll
    for (int t = 0; t < 2; t++) {
      int jl = (w * 2 + t) * 16 + lm;
      float b1 = ff1b[ch * 128 + jl];
#pragma unroll
      for (int m = 0; m < 4; m++) {
        int sb = m * 16 + lq * 4;
        f32x4 v = acc1[t][m];
#pragma unroll
        for (int r = 0; r < 4; r++) {
          float x = v[r] + b1;
          float sl = x / (1.f + __expf(-x));
          sH[(sb + r) * HPITCH + jl] = f2b(sl);
        }
      }
    }
    __syncthreads();  // sH ready
    // GEMM2 partial: K = this 128-j chunk; wave handles o-blocks {4w..4w+3}
#pragma unroll 2
    for (int k = 0; k < 4; ++k) {
      ABFrag a[4];
      int col = k * 32 + lq * 8;
#pragma unroll
      for (int m = 0; m < 4; m++) {
        int row = m * 16 + lm;
        a[m].h[0] = *(const bf16x4*)&sH[row * HPITCH + col];
        a[m].h[1] = *(const bf16x4*)&sH[row * HPITCH + col + 4];
      }
      int kg = ch * 4 + k;
#pragma unroll
      for (int t = 0; t < 4; t++) {
        int oblk = w * 4 + t;
        bf16x8 bf = *(const bf16x8*)(w2p + (((size_t)oblk * 16 + kg) * 64 + lane) * 8);
#pragma unroll
        for (int m = 0; m < 4; m++)
          acc2[t][m] = __builtin_amdgcn_mfma_f32_16x16x32_bf16(a[m].v, bf, acc2[t][m], 0, 0, 0);
      }
    }
  }

  // ---- epilogue: out[c][s] = out1 + ff2b + ff ----
#pragma unroll
  for (int t = 0; t < 4; t++) {
    int c = (w * 4 + t) * 16 + lm;
    float bias = ff2b[c];
#pragma unroll
    for (int m = 0; m < 4; m++) {
      int sb = m * 16 + lq * 4;
      f32x4 v = acc2[t][m];
      float4 ov;
      ov.x = v[0] + bias + b2f(sX[(sb + 0) * XPITCH + c]);
      ov.y = v[1] + bias + b2f(sX[(sb + 1) * XPITCH + c]);
      ov.z = v[2] + bias + b2f(sX[(sb + 2) * XPITCH + c]);
      ov.w = v[3] + bias + b2f(sX[(sb + 3) * XPITCH + c]);
      *(float4*)(out + (((size_t)(b * QC + c)) << 14) + s0 + sb) = ov;
    }
  }
}

extern "C" void kernel_launch(void* const* d_in, const int* in_sizes, int n_in,
                              void* d_out, int out_size, void* d_ws, size_t ws_size,
                              hipStream_t stream) {
  const float* feat   = (const float*)d_in[0];
  const float* tokens = (const float*)d_in[1];
  const float* qw     = (const float*)d_in[2];
  const float* qb     = (const float*)d_in[3];
  const float* kw     = (const float*)d_in[4];
  const float* vw     = (const float*)d_in[5];
  const float* projw  = (const float*)d_in[6];
  const float* projb  = (const float*)d_in[7];
  const float* ff1w   = (const float*)d_in[8];
  const float* ff1b   = (const float*)d_in[9];
  const float* ff2w   = (const float*)d_in[10];
  const float* ff2b   = (const float*)d_in[11];
  const float* gate   = (const float*)d_in[12];
  float* out = (float*)d_out;

  u16* w1p = (u16*)d_ws;                               // 256 KB
  u16* w2p = w1p + 131072;                             // 256 KB
  float* ws_kv = (float*)((char*)d_ws + 524288);       // 1 MB (K then V)

  pack_kernel<<<dim3(128), dim3(256), 0, stream>>>(ff1w, ff2w, w1p, w2p);
  kv_kernel<<<dim3(NB * NT), dim3(256), 0, stream>>>(tokens, kw, vw, gate, ws_kv);
  fused_kernel<<<dim3(NB * (SD / TSP)), dim3(256), 0, stream>>>(
      feat, qw, qb, projw, projb, ff1b, ff2b, w1p, w2p, gate, ws_kv, out);
}

// Round 4
// 199.266 us; speedup vs baseline: 10.5606x; 1.0276x over previous
//
#include <hip/hip_runtime.h>

// Problem constants (CrossAttention_73856257622246)
#define NB 4      // batch
#define QC 256    // query channels
#define SD 16384  // Z*H*W spatial per batch
#define NT 256    // tokens
#define KVC 512   // token channels
#define TC 128    // TOKEN_CH
#define NH 4      // heads
#define DH 32     // head dim
#define TSP 64    // spatial tile per block
#define XPITCH 260  // sX row pitch (256 + 4) -> bank stride 2, 8B-aligned rows
#define HPITCH 132  // sH row pitch (128 + 4)

typedef unsigned short u16;
typedef __attribute__((ext_vector_type(8))) short bf16x8;  // MFMA A/B frag (4 VGPR)
typedef __attribute__((ext_vector_type(4))) short bf16x4;  // 8B half-frag
typedef __attribute__((ext_vector_type(4))) float f32x4;   // MFMA C/D frag

union ABFrag { bf16x4 h[2]; bf16x8 v; };

__device__ __forceinline__ float b2f(u16 u) {
  unsigned int v = ((unsigned int)u) << 16;
  return __builtin_bit_cast(float, v);
}
__device__ __forceinline__ u16 f2b(float f) {
  unsigned int x = __builtin_bit_cast(unsigned int, f);
  unsigned int r = (x + 0x7fffu + ((x >> 16) & 1u)) >> 16;
  return (u16)r;
}

// ---- weight pre-pack: fp32 -> bf16 in MFMA B-fragment order ----
// B-frag layout (16x16x32): lane holds B[k][n], n = lane&15, k = (lane>>4)*8 + i
// w1p slot = (jblk*8 + kblk)*64 + lane   (jblk: 32, kblk: 8)
// w2p slot = (oblk*16 + kblk)*64 + lane  (oblk: 16, kblk: 16)
__global__ __launch_bounds__(256) void pack_kernel(
    const float* __restrict__ ff1w, const float* __restrict__ ff2w,
    u16* __restrict__ w1p, u16* __restrict__ w2p) {
  int idx = blockIdx.x * 256 + threadIdx.x;  // 0..32767
  int lane = idx & 63;
  int m = lane & 15, q = lane >> 4;
  if (idx < 16384) {
    int kblk = (idx >> 6) & 7;
    int jblk = idx >> 9;
    const float* src = ff1w + (size_t)(jblk * 16 + m) * QC + kblk * 32 + q * 8;
    u16* dst = w1p + (size_t)idx * 8;
#pragma unroll
    for (int i = 0; i < 8; i++) dst[i] = f2b(src[i]);
  } else {
    int s2 = idx - 16384;
    int kblk = (s2 >> 6) & 15;
    int oblk = s2 >> 10;
    const float* src = ff2w + (size_t)(oblk * 16 + m) * KVC + kblk * 32 + q * 8;
    u16* dst = w2p + (size_t)s2 * 8;
#pragma unroll
    for (int i = 0; i < 8; i++) dst[i] = f2b(src[i]);
  }
}

// ---- K/V precompute (only does work when tanh(gate) != 0) ----
__global__ __launch_bounds__(256) void kv_kernel(
    const float* __restrict__ tokens, const float* __restrict__ kw,
    const float* __restrict__ vw, const float* __restrict__ gate,
    float* __restrict__ ws_kv) {
  float tg = tanhf(gate[0]);
  if (tg == 0.0f) return;
  int b = blockIdx.x >> 8;
  int n = blockIdx.x & 255;
  __shared__ float tok[KVC];
  for (int c = threadIdx.x; c < KVC; c += 256)
    tok[c] = tokens[((size_t)(b * NT + n)) * KVC + c];
  __syncthreads();
  int tid = threadIdx.x;
  int t = tid & 127;
  const float* w = (tid < 128) ? kw : vw;
  const float* wr = w + (size_t)t * KVC;
  float acc = 0.f;
  for (int c = 0; c < KVC; c += 4) {
    float4 wv = *(const float4*)(wr + c);
    acc += tok[c] * wv.x + tok[c + 1] * wv.y + tok[c + 2] * wv.z + tok[c + 3] * wv.w;
  }
  int h = t >> 5, d = t & 31;
  float* dst = ws_kv + ((tid < 128) ? 0 : NB * NH * NT * DH);
  dst[(((b * NH + h) * NT) + n) * DH + d] = acc;
}

// ---- fused: [attention+proj+gated residual if gate!=0] + MFMA FFN + residual ----
__global__ __launch_bounds__(256, 3) void fused_kernel(
    const float* __restrict__ feat, const float* __restrict__ qw,
    const float* __restrict__ qb, const float* __restrict__ projw,
    const float* __restrict__ projb, const float* __restrict__ ff1b,
    const float* __restrict__ ff2b, const u16* __restrict__ w1p,
    const u16* __restrict__ w2p, const float* __restrict__ gate,
    const float* __restrict__ ws_kv, float* __restrict__ out) {
  __shared__ u16 sX[TSP * XPITCH];  // feat/out1 tile, [s][c], 33280 B
  __shared__ u16 sH[TSP * HPITCH];  // hidden chunk / attn buf, [s][j], 16896 B

  int b = blockIdx.x >> 8;
  int s0 = (blockIdx.x & 255) * TSP;
  int tid = threadIdx.x;
  int w = tid >> 6;     // wave 0..3
  int lane = tid & 63;
  int lm = lane & 15, lq = lane >> 4;

  // ---- stage feat tile transposed: global [c][s] fp32 -> LDS [s][c] bf16 ----
  // 16 independent float4 loads/thread (256B contiguous per c-row per instr)
  {
    const float* fb = feat + (((size_t)b * QC) << 14) + s0;
    int cst = tid >> 4;         // c offset within 16-row group
    int ss = (tid & 15) * 4;    // s quad
#pragma unroll
    for (int it = 0; it < 16; ++it) {
      int c = it * 16 + cst;
      float4 v = *(const float4*)(fb + ((size_t)c << 14) + ss);
      sX[(ss + 0) * XPITCH + c] = f2b(v.x);
      sX[(ss + 1) * XPITCH + c] = f2b(v.y);
      sX[(ss + 2) * XPITCH + c] = f2b(v.z);
      sX[(ss + 3) * XPITCH + c] = f2b(v.w);
    }
  }
  float tg = tanhf(gate[0]);
  __syncthreads();

  if (tg != 0.0f) {
    // ---- Q for head w, spatial position `lane` ----
    float qreg[DH];
#pragma unroll
    for (int d = 0; d < DH; d++) {
      int o = w * DH + d;
      float a = qb[o];
      const float* qr = qw + (size_t)o * QC;
      for (int c = 0; c < QC; c += 4) {
        float4 wv = *(const float4*)(qr + c);
        a += b2f(sX[lane * XPITCH + c + 0]) * wv.x;
        a += b2f(sX[lane * XPITCH + c + 1]) * wv.y;
        a += b2f(sX[lane * XPITCH + c + 2]) * wv.z;
        a += b2f(sX[lane * XPITCH + c + 3]) * wv.w;
      }
      qreg[d] = a;
    }
    // ---- online-softmax attention over NT tokens ----
    const float* Kp = ws_kv + (size_t)(b * NH + w) * NT * DH;
    const float* Vp = Kp + NB * NH * NT * DH;
    float m_ = -1e30f, l_ = 0.f;
    float oacc[DH];
#pragma unroll
    for (int d = 0; d < DH; d++) oacc[d] = 0.f;
    const float scale = 0.17677669529663687f;  // 1/sqrt(32)
    for (int n = 0; n < NT; n++) {
      const float* kr = Kp + n * DH;
      float s = 0.f;
#pragma unroll
      for (int d = 0; d < DH; d++) s += qreg[d] * kr[d];
      s *= scale;
      float nm = fmaxf(m_, s);
      float p = __expf(s - nm);
      float al = __expf(m_ - nm);
      const float* vr = Vp + n * DH;
      l_ = l_ * al + p;
#pragma unroll
      for (int d = 0; d < DH; d++) oacc[d] = oacc[d] * al + p * vr[d];
      m_ = nm;
    }
    float inv = 1.0f / l_;
#pragma unroll
    for (int d = 0; d < DH; d++)
      sH[lane * HPITCH + w * DH + d] = f2b(oacc[d] * inv);  // sattn [s][t=128]
    __syncthreads();
    // ---- proj + gated residual into sX (wave w owns channels w*64..+64) ----
    for (int ci = 0; ci < 64; ci++) {
      int c = w * 64 + ci;
      float a = projb[c];
      const float* pr = projw + (size_t)c * TC;
      for (int t = 0; t < TC; t += 4) {
        float4 wv = *(const float4*)(pr + t);
        a += b2f(sH[lane * HPITCH + t + 0]) * wv.x;
        a += b2f(sH[lane * HPITCH + t + 1]) * wv.y;
        a += b2f(sH[lane * HPITCH + t + 2]) * wv.z;
        a += b2f(sH[lane * HPITCH + t + 3]) * wv.w;
      }
      float o1 = b2f(sX[lane * XPITCH + c]) + tg * a;
      sX[lane * XPITCH + c] = f2b(o1);
    }
    __syncthreads();
  }

  // ---- MFMA FFN with software-pipelined B-fragment loads ----
  const f32x4 fzero = {0.f, 0.f, 0.f, 0.f};
  f32x4 acc2[4][4];  // [t = o-block][m = s-block]
#pragma unroll
  for (int t = 0; t < 4; t++)
#pragma unroll
    for (int m = 0; m < 4; m++) acc2[t][m] = fzero;

#pragma unroll 1
  for (int ch = 0; ch < 4; ++ch) {
    // GEMM1: H^T[s=64][j-chunk=128] ; wave handles j-blocks {2w, 2w+1}
    f32x4 acc1[2][4];
#pragma unroll
    for (int t = 0; t < 2; t++)
#pragma unroll
      for (int m = 0; m < 4; m++) acc1[t][m] = fzero;

    {
      int jb0 = ch * 8 + w * 2;
      const u16* bp0 = w1p + ((size_t)(jb0 + 0) * 8 * 64 + lane) * 8;
      const u16* bp1 = w1p + ((size_t)(jb0 + 1) * 8 * 64 + lane) * 8;
      // preload k=0 B pair
      bf16x8 b0 = *(const bf16x8*)bp0;
      bf16x8 b1 = *(const bf16x8*)bp1;
#pragma unroll
      for (int k = 0; k < 8; ++k) {
        // A frags for this k
        ABFrag a[4];
        int col = k * 32 + lq * 8;
#pragma unroll
        for (int m = 0; m < 4; m++) {
          int row = m * 16 + lm;
          a[m].h[0] = *(const bf16x4*)&sX[row * XPITCH + col];
          a[m].h[1] = *(const bf16x4*)&sX[row * XPITCH + col + 4];
        }
        // prefetch k+1 B pair
        bf16x8 n0, n1;
        if (k < 7) {
          n0 = *(const bf16x8*)(bp0 + (size_t)(k + 1) * 64 * 8);
          n1 = *(const bf16x8*)(bp1 + (size_t)(k + 1) * 64 * 8);
        }
#pragma unroll
        for (int m = 0; m < 4; m++)
          acc1[0][m] = __builtin_amdgcn_mfma_f32_16x16x32_bf16(a[m].v, b0, acc1[0][m], 0, 0, 0);
#pragma unroll
        for (int m = 0; m < 4; m++)
          acc1[1][m] = __builtin_amdgcn_mfma_f32_16x16x32_bf16(a[m].v, b1, acc1[1][m], 0, 0, 0);
        if (k < 7) { b0 = n0; b1 = n1; }
      }
    }
    __syncthreads();  // previous chunk's GEMM2 reads of sH complete
    // bias + SiLU -> sH[s][j_local]
#pragma unroll
    for (int t = 0; t < 2; t++) {
      int jl = (w * 2 + t) * 16 + lm;
      float b1v = ff1b[ch * 128 + jl];
#pragma unroll
      for (int m = 0; m < 4; m++) {
        int sb = m * 16 + lq * 4;
        f32x4 v = acc1[t][m];
#pragma unroll
        for (int r = 0; r < 4; r++) {
          float x = v[r] + b1v;
          float sl = x / (1.f + __expf(-x));
          sH[(sb + r) * HPITCH + jl] = f2b(sl);
        }
      }
    }
    __syncthreads();  // sH ready
    // GEMM2 partial: K = this 128-j chunk; wave handles o-blocks {4w..4w+3}
    {
      const u16* bp[4];
      bf16x8 bb[4];
#pragma unroll
      for (int t = 0; t < 4; t++) {
        int oblk = w * 4 + t;
        bp[t] = w2p + ((size_t)(oblk * 16 + ch * 4) * 64 + lane) * 8;
        bb[t] = *(const bf16x8*)bp[t];  // preload k=0
      }
#pragma unroll
      for (int k = 0; k < 4; ++k) {
        ABFrag a[4];
        int col = k * 32 + lq * 8;
#pragma unroll
        for (int m = 0; m < 4; m++) {
          int row = m * 16 + lm;
          a[m].h[0] = *(const bf16x4*)&sH[row * HPITCH + col];
          a[m].h[1] = *(const bf16x4*)&sH[row * HPITCH + col + 4];
        }
        bf16x8 nb[4];
        if (k < 3) {
#pragma unroll
          for (int t = 0; t < 4; t++)
            nb[t] = *(const bf16x8*)(bp[t] + (size_t)(k + 1) * 64 * 8);
        }
#pragma unroll
        for (int t = 0; t < 4; t++)
#pragma unroll
          for (int m = 0; m < 4; m++)
            acc2[t][m] = __builtin_amdgcn_mfma_f32_16x16x32_bf16(a[m].v, bb[t], acc2[t][m], 0, 0, 0);
        if (k < 3) {
#pragma unroll
          for (int t = 0; t < 4; t++) bb[t] = nb[t];
        }
      }
    }
  }

  // ---- epilogue: out[c][s] = out1 + ff2b + ff ----
#pragma unroll
  for (int t = 0; t < 4; t++) {
    int c = (w * 4 + t) * 16 + lm;
    float bias = ff2b[c];
#pragma unroll
    for (int m = 0; m < 4; m++) {
      int sb = m * 16 + lq * 4;
      f32x4 v = acc2[t][m];
      float4 ov;
      ov.x = v[0] + bias + b2f(sX[(sb + 0) * XPITCH + c]);
      ov.y = v[1] + bias + b2f(sX[(sb + 1) * XPITCH + c]);
      ov.z = v[2] + bias + b2f(sX[(sb + 2) * XPITCH + c]);
      ov.w = v[3] + bias + b2f(sX[(sb + 3) * XPITCH + c]);
      *(float4*)(out + (((size_t)(b * QC + c)) << 14) + s0 + sb) = ov;
    }
  }
}

extern "C" void kernel_launch(void* const* d_in, const int* in_sizes, int n_in,
                              void* d_out, int out_size, void* d_ws, size_t ws_size,
                              hipStream_t stream) {
  const float* feat   = (const float*)d_in[0];
  const float* tokens = (const float*)d_in[1];
  const float* qw     = (const float*)d_in[2];
  const float* qb     = (const float*)d_in[3];
  const float* kw     = (const float*)d_in[4];
  const float* vw     = (const float*)d_in[5];
  const float* projw  = (const float*)d_in[6];
  const float* projb  = (const float*)d_in[7];
  const float* ff1w   = (const float*)d_in[8];
  const float* ff1b   = (const float*)d_in[9];
  const float* ff2w   = (const float*)d_in[10];
  const float* ff2b   = (const float*)d_in[11];
  const float* gate   = (const float*)d_in[12];
  float* out = (float*)d_out;

  u16* w1p = (u16*)d_ws;                               // 256 KB
  u16* w2p = w1p + 131072;                             // 256 KB
  float* ws_kv = (float*)((char*)d_ws + 524288);       // 1 MB (K then V)

  pack_kernel<<<dim3(128), dim3(256), 0, stream>>>(ff1w, ff2w, w1p, w2p);
  kv_kernel<<<dim3(NB * NT), dim3(256), 0, stream>>>(tokens, kw, vw, gate, ws_kv);
  fused_kernel<<<dim3(NB * (SD / TSP)), dim3(256), 0, stream>>>(
      feat, qw, qb, projw, projb, ff1b, ff2b, w1p, w2p, gate, ws_kv, out);
}

// Round 5
// 174.885 us; speedup vs baseline: 12.0329x; 1.1394x over previous
//
#include <hip/hip_runtime.h>

// Problem constants (CrossAttention_73856257622246)
#define NB 4      // batch
#define QC 256    // query channels
#define SD 16384  // Z*H*W spatial per batch
#define NT 256    // tokens
#define KVC 512   // token channels
#define TC 128    // TOKEN_CH
#define NH 4      // heads
#define DH 32     // head dim
#define TSP 64    // spatial tile per block
#define XPITCH 264  // sX row pitch (mult of 8 -> 16B-aligned rows, bank stride 4)
#define HPITCH 136  // sH row pitch (mult of 8)

typedef unsigned short u16;
typedef unsigned int u32;
typedef __attribute__((ext_vector_type(8))) short bf16x8;  // MFMA A/B frag (4 VGPR)
typedef __attribute__((ext_vector_type(4))) float f32x4;   // MFMA C/D frag

__device__ __forceinline__ float b2f(u16 u) {
  unsigned int v = ((unsigned int)u) << 16;
  return __builtin_bit_cast(float, v);
}
__device__ __forceinline__ u16 f2b(float f) {  // RNE (used in cold paths / packing)
  unsigned int x = __builtin_bit_cast(unsigned int, f);
  unsigned int r = (x + 0x7fffu + ((x >> 16) & 1u)) >> 16;
  return (u16)r;
}
__device__ __forceinline__ u16 f2b_fast(float f) {  // round-half-up, 2 VALU
  return (u16)((__builtin_bit_cast(unsigned int, f) + 0x8000u) >> 16);
}
// pack bf16(a) into low16, bf16(b) into high16 — 2 adds + 1 v_perm
__device__ __forceinline__ u32 pk2(float a, float b) {
  u32 ua = __builtin_bit_cast(u32, a) + 0x8000u;
  u32 ub = __builtin_bit_cast(u32, b) + 0x8000u;
  return __builtin_amdgcn_perm(ub, ua, 0x07060302u);
}

// ---- weight pre-pack: fp32 -> bf16 in MFMA B-fragment order ----
// B-frag layout (16x16x32): lane holds B[k][n], n = lane&15, k = (lane>>4)*8 + i
// w1p slot = (jblk*8 + kblk)*64 + lane   (jblk: 32, kblk: 8)
// w2p slot = (oblk*16 + kblk)*64 + lane  (oblk: 16, kblk: 16)
__global__ __launch_bounds__(256) void pack_kernel(
    const float* __restrict__ ff1w, const float* __restrict__ ff2w,
    u16* __restrict__ w1p, u16* __restrict__ w2p) {
  int idx = blockIdx.x * 256 + threadIdx.x;  // 0..32767
  int lane = idx & 63;
  int m = lane & 15, q = lane >> 4;
  if (idx < 16384) {
    int kblk = (idx >> 6) & 7;
    int jblk = idx >> 9;
    const float* src = ff1w + (size_t)(jblk * 16 + m) * QC + kblk * 32 + q * 8;
    u16* dst = w1p + (size_t)idx * 8;
#pragma unroll
    for (int i = 0; i < 8; i++) dst[i] = f2b(src[i]);
  } else {
    int s2 = idx - 16384;
    int kblk = (s2 >> 6) & 15;
    int oblk = s2 >> 10;
    const float* src = ff2w + (size_t)(oblk * 16 + m) * KVC + kblk * 32 + q * 8;
    u16* dst = w2p + (size_t)s2 * 8;
#pragma unroll
    for (int i = 0; i < 8; i++) dst[i] = f2b(src[i]);
  }
}

// ---- K/V precompute (only does work when tanh(gate) != 0) ----
__global__ __launch_bounds__(256) void kv_kernel(
    const float* __restrict__ tokens, const float* __restrict__ kw,
    const float* __restrict__ vw, const float* __restrict__ gate,
    float* __restrict__ ws_kv) {
  float tg = tanhf(gate[0]);
  if (tg == 0.0f) return;
  int b = blockIdx.x >> 8;
  int n = blockIdx.x & 255;
  __shared__ float tok[KVC];
  for (int c = threadIdx.x; c < KVC; c += 256)
    tok[c] = tokens[((size_t)(b * NT + n)) * KVC + c];
  __syncthreads();
  int tid = threadIdx.x;
  int t = tid & 127;
  const float* w = (tid < 128) ? kw : vw;
  const float* wr = w + (size_t)t * KVC;
  float acc = 0.f;
  for (int c = 0; c < KVC; c += 4) {
    float4 wv = *(const float4*)(wr + c);
    acc += tok[c] * wv.x + tok[c + 1] * wv.y + tok[c + 2] * wv.z + tok[c + 3] * wv.w;
  }
  int h = t >> 5, d = t & 31;
  float* dst = ws_kv + ((tid < 128) ? 0 : NB * NH * NT * DH);
  dst[(((b * NH + h) * NT) + n) * DH + d] = acc;
}

// ---- fused: [attention+proj+gated residual if gate!=0] + MFMA FFN + residual ----
__global__ __launch_bounds__(256, 3) void fused_kernel(
    const float* __restrict__ feat, const float* __restrict__ qw,
    const float* __restrict__ qb, const float* __restrict__ projw,
    const float* __restrict__ projb, const float* __restrict__ ff1b,
    const float* __restrict__ ff2b, const u16* __restrict__ w1p,
    const u16* __restrict__ w2p, const float* __restrict__ gate,
    const float* __restrict__ ws_kv, float* __restrict__ out) {
  __shared__ u16 sX[TSP * XPITCH];  // feat/out1 tile, [s][c], 33792 B
  __shared__ u16 sH[TSP * HPITCH];  // hidden chunk / attn buf, [s][j], 17408 B

  int b = blockIdx.x >> 8;
  int s0 = (blockIdx.x & 255) * TSP;
  int tid = threadIdx.x;
  int w = tid >> 6;     // wave 0..3
  int lane = tid & 63;
  int lm = lane & 15, lq = lane >> 4;

  // ---- stage feat tile transposed: global [c][s] fp32 -> LDS [s][c] bf16 ----
  // per thread: 4 iters x (4 c-rows x 4 s) float4 loads, perm-packed b64 LDS writes
  {
    const float* fb = feat + (((size_t)b * QC) << 14) + s0;
    int cq = (tid >> 4) * 4;   // c quad base 0..60
    int sq = (tid & 15) * 4;   // s quad
#pragma unroll
    for (int it = 0; it < 4; ++it) {
      int c = it * 64 + cq;
      float4 r0 = *(const float4*)(fb + ((size_t)(c + 0) << 14) + sq);
      float4 r1 = *(const float4*)(fb + ((size_t)(c + 1) << 14) + sq);
      float4 r2 = *(const float4*)(fb + ((size_t)(c + 2) << 14) + sq);
      float4 r3 = *(const float4*)(fb + ((size_t)(c + 3) << 14) + sq);
      uint2 d0, d1, d2, d3;
      d0.x = pk2(r0.x, r1.x); d0.y = pk2(r2.x, r3.x);
      d1.x = pk2(r0.y, r1.y); d1.y = pk2(r2.y, r3.y);
      d2.x = pk2(r0.z, r1.z); d2.y = pk2(r2.z, r3.z);
      d3.x = pk2(r0.w, r1.w); d3.y = pk2(r2.w, r3.w);
      *(uint2*)&sX[(sq + 0) * XPITCH + c] = d0;
      *(uint2*)&sX[(sq + 1) * XPITCH + c] = d1;
      *(uint2*)&sX[(sq + 2) * XPITCH + c] = d2;
      *(uint2*)&sX[(sq + 3) * XPITCH + c] = d3;
    }
  }
  float tg = tanhf(gate[0]);
  __syncthreads();

  if (tg != 0.0f) {
    // ---- Q for head w, spatial position `lane` ----
    float qreg[DH];
#pragma unroll
    for (int d = 0; d < DH; d++) {
      int o = w * DH + d;
      float a = qb[o];
      const float* qr = qw + (size_t)o * QC;
      for (int c = 0; c < QC; c += 4) {
        float4 wv = *(const float4*)(qr + c);
        a += b2f(sX[lane * XPITCH + c + 0]) * wv.x;
        a += b2f(sX[lane * XPITCH + c + 1]) * wv.y;
        a += b2f(sX[lane * XPITCH + c + 2]) * wv.z;
        a += b2f(sX[lane * XPITCH + c + 3]) * wv.w;
      }
      qreg[d] = a;
    }
    // ---- online-softmax attention over NT tokens ----
    const float* Kp = ws_kv + (size_t)(b * NH + w) * NT * DH;
    const float* Vp = Kp + NB * NH * NT * DH;
    float m_ = -1e30f, l_ = 0.f;
    float oacc[DH];
#pragma unroll
    for (int d = 0; d < DH; d++) oacc[d] = 0.f;
    const float scale = 0.17677669529663687f;  // 1/sqrt(32)
    for (int n = 0; n < NT; n++) {
      const float* kr = Kp + n * DH;
      float s = 0.f;
#pragma unroll
      for (int d = 0; d < DH; d++) s += qreg[d] * kr[d];
      s *= scale;
      float nm = fmaxf(m_, s);
      float p = __expf(s - nm);
      float al = __expf(m_ - nm);
      const float* vr = Vp + n * DH;
      l_ = l_ * al + p;
#pragma unroll
      for (int d = 0; d < DH; d++) oacc[d] = oacc[d] * al + p * vr[d];
      m_ = nm;
    }
    float inv = 1.0f / l_;
#pragma unroll
    for (int d = 0; d < DH; d++)
      sH[lane * HPITCH + w * DH + d] = f2b(oacc[d] * inv);  // sattn [s][t=128]
    __syncthreads();
    // ---- proj + gated residual into sX (wave w owns channels w*64..+64) ----
    for (int ci = 0; ci < 64; ci++) {
      int c = w * 64 + ci;
      float a = projb[c];
      const float* pr = projw + (size_t)c * TC;
      for (int t = 0; t < TC; t += 4) {
        float4 wv = *(const float4*)(pr + t);
        a += b2f(sH[lane * HPITCH + t + 0]) * wv.x;
        a += b2f(sH[lane * HPITCH + t + 1]) * wv.y;
        a += b2f(sH[lane * HPITCH + t + 2]) * wv.z;
        a += b2f(sH[lane * HPITCH + t + 3]) * wv.w;
      }
      float o1 = b2f(sX[lane * XPITCH + c]) + tg * a;
      sX[lane * XPITCH + c] = f2b(o1);
    }
    __syncthreads();
  }

  // ---- MFMA FFN; biases folded into accumulator init ----
  f32x4 acc2[4][4];  // [t = o-block][m = s-block]
#pragma unroll
  for (int t = 0; t < 4; t++) {
    float b2v = ff2b[(w * 4 + t) * 16 + lm];
    f32x4 iv = {b2v, b2v, b2v, b2v};
#pragma unroll
    for (int m = 0; m < 4; m++) acc2[t][m] = iv;
  }

#pragma unroll 1
  for (int ch = 0; ch < 4; ++ch) {
    // GEMM1: H^T[s=64][j-chunk=128] ; wave handles j-blocks {2w, 2w+1}
    f32x4 acc1[2][4];
#pragma unroll
    for (int t = 0; t < 2; t++) {
      float b1v = ff1b[ch * 128 + (w * 2 + t) * 16 + lm];
      f32x4 iv = {b1v, b1v, b1v, b1v};
#pragma unroll
      for (int m = 0; m < 4; m++) acc1[t][m] = iv;
    }
    {
      int jb0 = ch * 8 + w * 2;
      const u16* p0 = w1p + (((size_t)(jb0 + 0) * 8) * 64 + lane) * 8;
      const u16* p1 = w1p + (((size_t)(jb0 + 1) * 8) * 64 + lane) * 8;
      // depth-2 B pipeline (stride per k-step: 512 u16)
      bf16x8 c0 = *(const bf16x8*)(p0);
      bf16x8 c1 = *(const bf16x8*)(p1);
      bf16x8 n0 = *(const bf16x8*)(p0 + 512);
      bf16x8 n1 = *(const bf16x8*)(p1 + 512);
#pragma unroll
      for (int k = 0; k < 8; ++k) {
        bf16x8 f0, f1;
        if (k < 6) {
          f0 = *(const bf16x8*)(p0 + (size_t)(k + 2) * 512);
          f1 = *(const bf16x8*)(p1 + (size_t)(k + 2) * 512);
        }
        bf16x8 a[4];
        int col = k * 32 + lq * 8;
#pragma unroll
        for (int m = 0; m < 4; m++)
          a[m] = *(const bf16x8*)&sX[(m * 16 + lm) * XPITCH + col];
#pragma unroll
        for (int m = 0; m < 4; m++)
          acc1[0][m] = __builtin_amdgcn_mfma_f32_16x16x32_bf16(a[m], c0, acc1[0][m], 0, 0, 0);
#pragma unroll
        for (int m = 0; m < 4; m++)
          acc1[1][m] = __builtin_amdgcn_mfma_f32_16x16x32_bf16(a[m], c1, acc1[1][m], 0, 0, 0);
        c0 = n0; c1 = n1;
        if (k < 6) { n0 = f0; n1 = f1; }
      }
    }
    __syncthreads();  // previous chunk's GEMM2 reads of sH complete
    // SiLU (bias already in acc) -> sH[s][j_local]
#pragma unroll
    for (int t = 0; t < 2; t++) {
      int jl = (w * 2 + t) * 16 + lm;
#pragma unroll
      for (int m = 0; m < 4; m++) {
        int sb = m * 16 + lq * 4;
        f32x4 v = acc1[t][m];
#pragma unroll
        for (int r = 0; r < 4; r++) {
          float x = v[r];
          float sl = x * __builtin_amdgcn_rcpf(1.f + __expf(-x));
          sH[(sb + r) * HPITCH + jl] = f2b_fast(sl);
        }
      }
    }
    __syncthreads();  // sH ready
    // GEMM2 partial: K = this 128-j chunk; wave handles o-blocks {4w..4w+3}
    {
      const u16* qp[4];
#pragma unroll
      for (int t = 0; t < 4; t++)
        qp[t] = w2p + (((size_t)((w * 4 + t) * 16 + ch * 4)) * 64 + lane) * 8;
      bf16x8 cc[4], nn[4];
#pragma unroll
      for (int t = 0; t < 4; t++) cc[t] = *(const bf16x8*)(qp[t]);
#pragma unroll
      for (int t = 0; t < 4; t++) nn[t] = *(const bf16x8*)(qp[t] + 512);
#pragma unroll
      for (int k = 0; k < 4; ++k) {
        bf16x8 ff[4];
        if (k < 2) {
#pragma unroll
          for (int t = 0; t < 4; t++)
            ff[t] = *(const bf16x8*)(qp[t] + (size_t)(k + 2) * 512);
        }
        bf16x8 a[4];
        int col = k * 32 + lq * 8;
#pragma unroll
        for (int m = 0; m < 4; m++)
          a[m] = *(const bf16x8*)&sH[(m * 16 + lm) * HPITCH + col];
#pragma unroll
        for (int t = 0; t < 4; t++)
#pragma unroll
          for (int m = 0; m < 4; m++)
            acc2[t][m] = __builtin_amdgcn_mfma_f32_16x16x32_bf16(a[m], cc[t], acc2[t][m], 0, 0, 0);
#pragma unroll
        for (int t = 0; t < 4; t++) cc[t] = nn[t];
        if (k < 2) {
#pragma unroll
          for (int t = 0; t < 4; t++) nn[t] = ff[t];
        }
      }
    }
  }

  // ---- epilogue: out[c][s] = out1 + ff (bias already in acc2) ----
#pragma unroll
  for (int t = 0; t < 4; t++) {
    int c = (w * 4 + t) * 16 + lm;
#pragma unroll
    for (int m = 0; m < 4; m++) {
      int sb = m * 16 + lq * 4;
      f32x4 v = acc2[t][m];
      float4 ov;
      ov.x = v[0] + b2f(sX[(sb + 0) * XPITCH + c]);
      ov.y = v[1] + b2f(sX[(sb + 1) * XPITCH + c]);
      ov.z = v[2] + b2f(sX[(sb + 2) * XPITCH + c]);
      ov.w = v[3] + b2f(sX[(sb + 3) * XPITCH + c]);
      *(float4*)(out + (((size_t)(b * QC + c)) << 14) + s0 + sb) = ov;
    }
  }
}

extern "C" void kernel_launch(void* const* d_in, const int* in_sizes, int n_in,
                              void* d_out, int out_size, void* d_ws, size_t ws_size,
                              hipStream_t stream) {
  const float* feat   = (const float*)d_in[0];
  const float* tokens = (const float*)d_in[1];
  const float* qw     = (const float*)d_in[2];
  const float* qb     = (const float*)d_in[3];
  const float* kw     = (const float*)d_in[4];
  const float* vw     = (const float*)d_in[5];
  const float* projw  = (const float*)d_in[6];
  const float* projb  = (const float*)d_in[7];
  const float* ff1w   = (const float*)d_in[8];
  const float* ff1b   = (const float*)d_in[9];
  const float* ff2w   = (const float*)d_in[10];
  const float* ff2b   = (const float*)d_in[11];
  const float* gate   = (const float*)d_in[12];
  float* out = (float*)d_out;

  u16* w1p = (u16*)d_ws;                               // 256 KB
  u16* w2p = w1p + 131072;                             // 256 KB
  float* ws_kv = (float*)((char*)d_ws + 524288);       // 1 MB (K then V)

  pack_kernel<<<dim3(128), dim3(256), 0, stream>>>(ff1w, ff2w, w1p, w2p);
  kv_kernel<<<dim3(NB * NT), dim3(256), 0, stream>>>(tokens, kw, vw, gate, ws_kv);
  fused_kernel<<<dim3(NB * (SD / TSP)), dim3(256), 0, stream>>>(
      feat, qw, qb, projw, projb, ff1b, ff2b, w1p, w2p, gate, ws_kv, out);
}